// Round 3
// baseline (59.734 us; speedup 1.0000x reference)
//
#include <hip/hip_runtime.h>

#define OUTN 400
#define THRESH 0.7f
#define BB 32
#define HH 512
#define WW 512
#define CC 3
#define CHUNKS 16

// bounds layout per batch: [minR, maxR, minC, maxC]
__global__ void init_bounds_kernel(int* __restrict__ bounds) {
    int i = threadIdx.x;
    if (i < BB * 4) {
        int which = i & 3;
        bounds[i] = (which == 0 || which == 2) ? 0x7FFFFFFF : -1;
    }
}

__global__ void bounds_kernel(const float* __restrict__ tensor,
                              int* __restrict__ bounds) {
    const int blk   = blockIdx.x;
    const int b     = blk / CHUNKS;
    const int chunk = blk % CHUNKS;
    const int rows_per_chunk = HH / CHUNKS;          // 32
    const int f4_per_row     = WW / 4;               // 128
    const int n4             = rows_per_chunk * f4_per_row; // 4096

    const float4* base = (const float4*)(tensor + (size_t)b * HH * WW
                                                + (size_t)chunk * rows_per_chunk * WW);

    int minR = 0x7FFFFFFF, maxR = -1, minC = 0x7FFFFFFF, maxC = -1;

    for (int p = threadIdx.x; p < n4; p += blockDim.x) {
        float4 v = base[p];
        int row  = p / f4_per_row;            // chunk-relative
        int col0 = (p % f4_per_row) * 4;
        bool m0 = v.x > THRESH, m1 = v.y > THRESH, m2 = v.z > THRESH, m3 = v.w > THRESH;
        if (m0 | m1 | m2 | m3) {
            minR = min(minR, row);
            maxR = max(maxR, row);
            if (m0) { minC = min(minC, col0    ); maxC = max(maxC, col0    ); }
            if (m1) { minC = min(minC, col0 + 1); maxC = max(maxC, col0 + 1); }
            if (m2) { minC = min(minC, col0 + 2); maxC = max(maxC, col0 + 2); }
            if (m3) { minC = min(minC, col0 + 3); maxC = max(maxC, col0 + 3); }
        }
    }

    // 64-lane wave reduction
    #pragma unroll
    for (int off = 32; off > 0; off >>= 1) {
        minR = min(minR, __shfl_down(minR, off));
        maxR = max(maxR, __shfl_down(maxR, off));
        minC = min(minC, __shfl_down(minC, off));
        maxC = max(maxC, __shfl_down(maxC, off));
    }

    __shared__ int s[4];
    if (threadIdx.x == 0) { s[0] = 0x7FFFFFFF; s[1] = -1; s[2] = 0x7FFFFFFF; s[3] = -1; }
    __syncthreads();
    if ((threadIdx.x & 63) == 0) {
        atomicMin(&s[0], minR); atomicMax(&s[1], maxR);
        atomicMin(&s[2], minC); atomicMax(&s[3], maxC);
    }
    __syncthreads();
    if (threadIdx.x == 0 && s[1] >= 0) {
        int rbase = chunk * rows_per_chunk;
        atomicMin(&bounds[b * 4 + 0], s[0] + rbase);
        atomicMax(&bounds[b * 4 + 1], s[1] + rbase);
        atomicMin(&bounds[b * 4 + 2], s[2]);
        atomicMax(&bounds[b * 4 + 3], s[3]);
    }
}

// One block per (batch, output row). 128 threads.
// Stage source rows r0 and r1 (512 px * 3 ch = 1536 floats = 384 float4 each)
// into LDS with coalesced float4 loads, then threads 0..99 each compute 4
// consecutive output pixels (12 floats) and store 3 aligned float4.
__global__ void __launch_bounds__(128) resize_kernel(
        const float* __restrict__ img,
        const int* __restrict__ bounds,
        float* __restrict__ out) {
    const int blk  = blockIdx.x;
    const int b    = blk / OUTN;
    const int orow = blk % OUTN;

    int minR = bounds[b * 4 + 0];
    int maxR = bounds[b * 4 + 1];
    int minC = bounds[b * 4 + 2];
    int maxC = bounds[b * 4 + 3];
    if (maxR < 0) { minR = 0; maxR = HH - 1; }
    if (maxC < 0) { minC = 0; maxC = WW - 1; }

    // row coords for this output row (matches _axis_coords exactly)
    float sizeR = (float)(maxR - minR);
    float srcR  = ((float)orow + 0.5f) * sizeR / (float)OUTN - 0.5f;
    srcR = fminf(fmaxf(srcR, 0.0f), fmaxf(sizeR - 1.0f, 0.0f));
    int   i0 = (int)floorf(srcR);
    int   i1 = min(i0 + 1, max(maxR - minR - 1, 0));
    float wr = srcR - (float)i0;
    int r0 = minR + i0, r1 = minR + i1;

    __shared__ float row0[WW * CC];  // 6 KB
    __shared__ float row1[WW * CC];  // 6 KB

    const float4* src0 = (const float4*)(img + ((size_t)b * HH + r0) * WW * CC);
    const float4* src1 = (const float4*)(img + ((size_t)b * HH + r1) * WW * CC);
    float4* l0 = (float4*)row0;
    float4* l1 = (float4*)row1;
    #pragma unroll
    for (int i = threadIdx.x; i < (WW * CC) / 4; i += 128) {   // 384 per row, 3 iters
        l0[i] = src0[i];
        l1[i] = src1[i];
    }
    __syncthreads();

    const int t = threadIdx.x;
    if (t < OUTN / 4) {                       // 100 active compute threads
        const float sizeC  = (float)(maxC - minC);
        const float hiClip = fmaxf(sizeC - 1.0f, 0.0f);
        const int   jmax   = max(maxC - minC - 1, 0);
        const float omw    = 1.0f - wr;

        float res[12];
        #pragma unroll
        for (int k = 0; k < 4; ++k) {
            int ocol = t * 4 + k;
            float srcC = ((float)ocol + 0.5f) * sizeC / (float)OUTN - 0.5f;
            srcC = fminf(fmaxf(srcC, 0.0f), hiClip);
            int   j0 = (int)floorf(srcC);
            int   j1 = min(j0 + 1, jmax);
            float wc = srcC - (float)j0;
            int c0 = (minC + j0) * CC;
            int c1 = (minC + j1) * CC;
            float omc = 1.0f - wc;
            #pragma unroll
            for (int ch = 0; ch < CC; ++ch) {
                float top = row0[c0 + ch] * omc + row0[c1 + ch] * wc;
                float bot = row1[c0 + ch] * omc + row1[c1 + ch] * wc;
                res[k * 3 + ch] = top * omw + bot * wr;
            }
        }

        float4* orow_ptr = (float4*)(out + ((size_t)b * OUTN + orow) * OUTN * CC);
        const float4* rv = (const float4*)res;
        orow_ptr[t * 3 + 0] = rv[0];
        orow_ptr[t * 3 + 1] = rv[1];
        orow_ptr[t * 3 + 2] = rv[2];
    }
}

extern "C" void kernel_launch(void* const* d_in, const int* in_sizes, int n_in,
                              void* d_out, int out_size, void* d_ws, size_t ws_size,
                              hipStream_t stream) {
    const float* image  = (const float*)d_in[0];
    const float* tensor = (const float*)d_in[1];
    float* out = (float*)d_out;
    int*   bounds = (int*)d_ws;

    hipLaunchKernelGGL(init_bounds_kernel, dim3(1), dim3(128), 0, stream, bounds);
    hipLaunchKernelGGL(bounds_kernel, dim3(BB * CHUNKS), dim3(256), 0, stream,
                       tensor, bounds);

    hipLaunchKernelGGL(resize_kernel, dim3(BB * OUTN), dim3(128), 0, stream,
                       image, bounds, out);
}

// Round 4
// 48.171 us; speedup vs baseline: 1.2400x; 1.2400x over previous
//
#include <hip/hip_runtime.h>

#define OUTN 400
#define THRESH 0.7f
#define BB 32
#define HH 512
#define WW 512
#define CC 3
#define CHUNKS 16
#define BIGI 0x7FFFFFFF

// Per-(batch,chunk) partial bounds, plain stores, no init / no global atomics.
// part[b*CHUNKS+chunk] = {minR, maxR, minC, maxC} in GLOBAL row coords;
// empty chunk => {BIGI, -1, BIGI, -1}.
__global__ void bounds_part_kernel(const float* __restrict__ tensor,
                                   int4* __restrict__ part) {
    const int blk   = blockIdx.x;
    const int b     = blk / CHUNKS;
    const int chunk = blk % CHUNKS;
    const int rows_per_chunk = HH / CHUNKS;          // 32
    const int f4_per_row     = WW / 4;               // 128
    const int n4             = rows_per_chunk * f4_per_row; // 4096

    const float4* base = (const float4*)(tensor + (size_t)b * HH * WW
                                                + (size_t)chunk * rows_per_chunk * WW);

    int minR = BIGI, maxR = -1, minC = BIGI, maxC = -1;

    for (int p = threadIdx.x; p < n4; p += blockDim.x) {
        float4 v = base[p];
        int row  = p / f4_per_row;            // chunk-relative
        int col0 = (p % f4_per_row) * 4;
        bool m0 = v.x > THRESH, m1 = v.y > THRESH, m2 = v.z > THRESH, m3 = v.w > THRESH;
        if (m0 | m1 | m2 | m3) {
            minR = min(minR, row);
            maxR = max(maxR, row);
            if (m0) { minC = min(minC, col0    ); maxC = max(maxC, col0    ); }
            if (m1) { minC = min(minC, col0 + 1); maxC = max(maxC, col0 + 1); }
            if (m2) { minC = min(minC, col0 + 2); maxC = max(maxC, col0 + 2); }
            if (m3) { minC = min(minC, col0 + 3); maxC = max(maxC, col0 + 3); }
        }
    }

    // 64-lane wave reduction
    #pragma unroll
    for (int off = 32; off > 0; off >>= 1) {
        minR = min(minR, __shfl_down(minR, off));
        maxR = max(maxR, __shfl_down(maxR, off));
        minC = min(minC, __shfl_down(minC, off));
        maxC = max(maxC, __shfl_down(maxC, off));
    }

    __shared__ int s[4];
    if (threadIdx.x == 0) { s[0] = BIGI; s[1] = -1; s[2] = BIGI; s[3] = -1; }
    __syncthreads();
    if ((threadIdx.x & 63) == 0) {
        atomicMin(&s[0], minR); atomicMax(&s[1], maxR);
        atomicMin(&s[2], minC); atomicMax(&s[3], maxC);
    }
    __syncthreads();
    if (threadIdx.x == 0) {
        int4 r;
        if (s[1] >= 0) {
            int rbase = chunk * rows_per_chunk;
            r.x = s[0] + rbase;   // minR global
            r.y = s[1] + rbase;   // maxR global
            r.z = s[2];           // minC
            r.w = s[3];           // maxC
        } else {
            r.x = BIGI; r.y = -1; r.z = BIGI; r.w = -1;
        }
        part[blk] = r;
    }
}

// 256-thread blocks, 1 output pixel per thread. 625 blocks per batch exactly,
// so every block serves a single batch. Bounds come from an in-wave butterfly
// reduction of the 16 chunk partials (no barrier, no atomics).
__global__ void __launch_bounds__(256) resize_kernel(
        const float* __restrict__ img,
        const int4* __restrict__ part,
        float* __restrict__ out) {
    const int idx = blockIdx.x * 256 + threadIdx.x;
    const int b   = blockIdx.x / (OUTN * OUTN / 256);   // 625 blocks/batch

    // each lane loads one of the 16 partials (replicated 4x across the wave);
    // xor-butterfly within 16-lane groups leaves the full reduction in every lane
    const int lane = threadIdx.x & 63;
    int4 p = part[b * CHUNKS + (lane & 15)];
    #pragma unroll
    for (int off = 1; off < 16; off <<= 1) {
        p.x = min(p.x, __shfl_xor(p.x, off));
        p.y = max(p.y, __shfl_xor(p.y, off));
        p.z = min(p.z, __shfl_xor(p.z, off));
        p.w = max(p.w, __shfl_xor(p.w, off));
    }
    int minR = p.x, maxR = p.y, minC = p.z, maxC = p.w;
    if (maxR < 0) { minR = 0; maxR = HH - 1; }   // all-false mask => [0, n-1]
    if (maxC < 0) { minC = 0; maxC = WW - 1; }

    const int ocol = idx % OUTN;
    const int orow = (idx / OUTN) % OUTN;

    // rows (matches _axis_coords exactly)
    float sizeR = (float)(maxR - minR);
    float srcR  = ((float)orow + 0.5f) * sizeR / (float)OUTN - 0.5f;
    srcR = fminf(fmaxf(srcR, 0.0f), fmaxf(sizeR - 1.0f, 0.0f));
    int   i0 = (int)floorf(srcR);
    int   i1 = min(i0 + 1, max(maxR - minR - 1, 0));
    float wr = srcR - (float)i0;
    int r0 = minR + i0, r1 = minR + i1;

    // cols
    float sizeC = (float)(maxC - minC);
    float srcC  = ((float)ocol + 0.5f) * sizeC / (float)OUTN - 0.5f;
    srcC = fminf(fmaxf(srcC, 0.0f), fmaxf(sizeC - 1.0f, 0.0f));
    int   j0 = (int)floorf(srcC);
    int   j1 = min(j0 + 1, max(maxC - minC - 1, 0));
    float wc = srcC - (float)j0;
    int c0 = minC + j0, c1 = minC + j1;

    const float* ib  = img + (size_t)b * HH * WW * CC;
    const float* p00 = ib + ((size_t)r0 * WW + c0) * CC;
    const float* p01 = ib + ((size_t)r0 * WW + c1) * CC;
    const float* p10 = ib + ((size_t)r1 * WW + c0) * CC;
    const float* p11 = ib + ((size_t)r1 * WW + c1) * CC;

    float* o = out + (size_t)idx * CC;
    #pragma unroll
    for (int ch = 0; ch < CC; ++ch) {
        float a00 = p00[ch], a01 = p01[ch], a10 = p10[ch], a11 = p11[ch];
        float top = a00 * (1.0f - wc) + a01 * wc;
        float bot = a10 * (1.0f - wc) + a11 * wc;
        o[ch] = top * (1.0f - wr) + bot * wr;
    }
}

extern "C" void kernel_launch(void* const* d_in, const int* in_sizes, int n_in,
                              void* d_out, int out_size, void* d_ws, size_t ws_size,
                              hipStream_t stream) {
    const float* image  = (const float*)d_in[0];
    const float* tensor = (const float*)d_in[1];
    float* out  = (float*)d_out;
    int4*  part = (int4*)d_ws;   // 512 * 16 B = 8 KB

    hipLaunchKernelGGL(bounds_part_kernel, dim3(BB * CHUNKS), dim3(256), 0, stream,
                       tensor, part);

    int total  = BB * OUTN * OUTN;            // 5,120,000
    int blocks = total / 256;                 // 20,000
    hipLaunchKernelGGL(resize_kernel, dim3(blocks), dim3(256), 0, stream,
                       image, part, out);
}